// Round 17
// baseline (4893.034 us; speedup 1.0000x reference)
//
#include <hip/hip_runtime.h>

// CustomGRU: B=256, T=1024, I=128, H=256.  out = concat(output[B,T,H], h_last[B,H]) f32.
//
// R17 = R16 + A/B phase interleave: each group's 4 batches split into two
// independent 2-batch recurrences. While phase A's exchange is in flight, phase B
// computes (and vice versa) -> the L2 publish->poll RTT (fully exposed in R16,
// ~500-900cyc/step) is hidden; polls hit on the first probe. Same W layout (12x4
// pinned f32x2/thread), same packed-u64 parity exchange, 3 barriers/iteration.

#define B_SZ 256
#define T_SZ 1024
#define H_SZ 256
#define G3   768
#define NGRP 64
#define SPIN_MAX (1 << 27)
#define HROW 288

typedef __attribute__((ext_vector_type(2))) float f32x2;

template<int CTRL>
__device__ __forceinline__ float dppx(float s) {
    return __int_as_float(
        __builtin_amdgcn_update_dpp(0, __float_as_int(s), CTRL, 0xF, 0xF, true));
}
template<int MASK>
__device__ __forceinline__ float swzx(float s) {
    return __int_as_float(__builtin_amdgcn_ds_swizzle(__float_as_int(s), MASK));
}
__device__ __forceinline__ f32x2 pkfma(f32x2 a, f32x2 b, f32x2 c) {
    f32x2 d;
    asm("v_pk_fma_f32 %0, %1, %2, %3" : "=v"(d) : "v"(a), "v"(b), "v"(c));
    return d;
}

// h position map: word k -> k + 4*(k>>5)  (injective; 4-word pad per 32 words)
static __device__ __forceinline__ int hpos(int k) { return k + 4 * (k >> 5); }

// slot: [g 64][par 2][n 4][unit 256] u64 = (ver<<32)|f32bits
static __device__ __forceinline__ size_t xsl(int g, int par, int n, int u) {
    return (((size_t)g * 2 + par) * 4 + n) * 256 + u;
}

// ---------------- prep ----------------
__global__ void prep_kernel(const float* __restrict__ h0,
                            unsigned long long* __restrict__ xch) {
    int tid = blockIdx.x * blockDim.x + threadIdx.x;
    if (tid < B_SZ * H_SZ) {
        int b = tid >> 8, u = tid & 255;
        int g = b >> 2, n = b & 3;
        unsigned long long val = (unsigned long long)__float_as_uint(h0[tid]);
        xch[xsl(g, 0, n, u)] = val;
        xch[xsl(g, 1, n, u)] = val;
    }
}

// ---------------- phase 1: gx = x @ W_ih^T (unchanged since R9) ----------------
__global__ __launch_bounds__(256) void gemm_x_kernel(
    const float* __restrict__ x, const float* __restrict__ wih,
    float* __restrict__ gx, int c, int tcShift)
{
    __shared__ __align__(16) float xs[64][132];
    __shared__ __align__(16) float ws[128][68];
    const int TC = 1 << tcShift;
    const int t  = threadIdx.x;
    const int bx = blockIdx.x, by = blockIdx.y;

#pragma unroll
    for (int i = 0; i < 8; ++i) {
        int f4 = t + i * 256;
        int r  = f4 >> 5, c4 = (f4 & 31) * 4;
        int rho = bx * 64 + r;
        int b = rho >> tcShift, u = rho & (TC - 1);
        float4 v = *(const float4*)(x + ((size_t)b * T_SZ + (size_t)c * TC + u) * 128 + c4);
        *(float4*)&xs[r][c4] = v;
    }

    const int gl = t & 31;
    const int rl = t >> 5;
    float acc[8][4];
#pragma unroll
    for (int i = 0; i < 8; ++i)
#pragma unroll
        for (int jj = 0; jj < 4; ++jj) acc[i][jj] = 0.f;

    for (int kb = 0; kb < 2; ++kb) {
        __syncthreads();
#pragma unroll
        for (int i = 0; i < 8; ++i) {
            int f4 = t + i * 256;
            int row = f4 >> 4, c4 = (f4 & 15) * 4;
            float4 v = *(const float4*)(wih + (size_t)(by * 128 + row) * 128 + kb * 64 + c4);
            *(float4*)&ws[row][c4] = v;
        }
        __syncthreads();

#pragma unroll 4
        for (int k4 = 0; k4 < 16; ++k4) {
            float4 wv0 = *(const float4*)&ws[gl     ][k4 * 4];
            float4 wv1 = *(const float4*)&ws[gl + 32][k4 * 4];
            float4 wv2 = *(const float4*)&ws[gl + 64][k4 * 4];
            float4 wv3 = *(const float4*)&ws[gl + 96][k4 * 4];
#pragma unroll
            for (int rr = 0; rr < 8; ++rr) {
                float4 xv = *(const float4*)&xs[rl + rr * 8][kb * 64 + k4 * 4];
                acc[rr][0] = fmaf(xv.w, wv0.w, fmaf(xv.z, wv0.z, fmaf(xv.y, wv0.y, fmaf(xv.x, wv0.x, acc[rr][0]))));
                acc[rr][1] = fmaf(xv.w, wv1.w, fmaf(xv.z, wv1.z, fmaf(xv.y, wv1.y, fmaf(xv.x, wv1.x, acc[rr][1]))));
                acc[rr][2] = fmaf(xv.w, wv2.w, fmaf(xv.z, wv2.z, fmaf(xv.y, wv2.y, fmaf(xv.x, wv2.x, acc[rr][2]))));
                acc[rr][3] = fmaf(xv.w, wv3.w, fmaf(xv.z, wv3.z, fmaf(xv.y, wv3.y, fmaf(xv.x, wv3.x, acc[rr][3]))));
            }
        }
    }

#pragma unroll
    for (int rr = 0; rr < 8; ++rr) {
        size_t base = (size_t)(bx * 64 + rl + rr * 8) * G3 + by * 128 + gl;
#pragma unroll
        for (int gi = 0; gi < 4; ++gi)
            gx[base + 32 * gi] = acc[rr][gi];
    }
}

#define PIN2(v) asm volatile("" : "+v"(v));

// ---------------- phase 2: recurrence, A/B interleaved ----------------
// grid 256 x 512. g = bid&63, m = bid>>6 (member, same XCD), u0 = 64m.
// Thread: q = t>>5 (unit quad uq=u0+4q), p = t&31 (8-k slice).
// Phase A = group batches {0,1} (slots n=0,1), phase B = {2,3} (n=2,3).
// Per phase: s[fam][i] = batch (i^(p&1)) partial; fam = gate*4 + unit-in-quad.
__global__ __launch_bounds__(512)
__attribute__((amdgpu_waves_per_eu(2, 2)))
void gru_kernel(
    const float* __restrict__ gx, const float* __restrict__ whh,
    const float* __restrict__ bih, const float* __restrict__ bhh,
    unsigned long long* __restrict__ xch, float* __restrict__ out,
    int gbase, int tc, int isLast)
{
    __shared__ __align__(16) float hlA[2][HROW];
    __shared__ __align__(16) float hlB[2][HROW];
    __shared__ __align__(16) float hst[4][64];

    const int t   = threadIdx.x;
    const int bid = blockIdx.x;
    const int g   = bid & 63;
    const int m   = bid >> 6;
    const int u0  = m * 64;
    const int q   = t >> 5;
    const int p   = t & 31;
    const int uq  = u0 + 4 * q;
    const int k0  = 8 * p;

    // ---- W: 12 fams (3 gates x 4 units) x 8 k = 48 pinned f32x2 ----
    f32x2 wf[12][4];
#pragma unroll
    for (int gate = 0; gate < 3; ++gate) {
#pragma unroll
        for (int e = 0; e < 4; ++e) {
            const float* wr = whh + (size_t)(gate * 256 + uq + e) * H_SZ + k0;
            float4 va = *(const float4*)(wr);
            float4 vb = *(const float4*)(wr + 4);
            wf[gate * 4 + e][0] = (f32x2){va.x, va.y};
            wf[gate * 4 + e][1] = (f32x2){va.z, va.w};
            wf[gate * 4 + e][2] = (f32x2){vb.x, vb.y};
            wf[gate * 4 + e][3] = (f32x2){vb.z, vb.w};
        }
    }
#pragma unroll
    for (int f = 0; f < 12; ++f) {
        PIN2(wf[f][0]) PIN2(wf[f][1]) PIN2(wf[f][2]) PIN2(wf[f][3])
    }

    // ---- gate-lane invariants: active lanes p<4; nb = p&1 (local batch),
    //      hi = (p>>1)&1 (unit pair) ----
    const int  nb  = p & 1;
    const int  hi  = (p >> 1) & 1;
    const bool act = (p < 4);
    const int  ueA = uq + 2 * hi;
    float bsr0 = 0.f, bsz0 = 0.f, bsn0 = 0.f, bsr1 = 0.f, bsz1 = 0.f, bsn1 = 0.f;
    const float* gxpA = nullptr;
    const float* gxpB = nullptr;
    if (act) {
        bsr0 = bih[ueA]       + bhh[ueA];
        bsz0 = bih[256 + ueA] + bhh[256 + ueA];
        bsn0 = bih[512 + ueA] + bhh[512 + ueA];
        bsr1 = bih[ueA + 1]   + bhh[ueA + 1];
        bsz1 = bih[257 + ueA] + bhh[257 + ueA];
        bsn1 = bih[513 + ueA] + bhh[513 + ueA];
        gxpA = gx + ((size_t)(4 * g + nb) * tc) * G3 + ueA;
        gxpB = gx + ((size_t)(4 * g + 2 + nb) * tc) * G3 + ueA;
    }

    // gather mapping: thread polls 1 slot (local batch n_loc, unit un)
    const int n_loc = t >> 8;
    const int un    = t & 255;
    const int wofs  = hpos(un);
    // matvec row pointers, hoisted
    const int Wd = hpos(k0);
    const float* hrA[2];
    const float* hrB[2];
#pragma unroll
    for (int i = 0; i < 2; ++i) {
        hrA[i] = &hlA[i ^ nb][Wd];
        hrB[i] = &hlB[i ^ nb][Wd];
    }
    const int pua = hpos(ueA);
    // out-store mapping (t<64)
    const int n_o = t >> 4, f_o = t & 15;

    // preload gx(u=0) for both phases
    float gArA = 0.f, gAzA = 0.f, gAnA = 0.f, gArB = 0.f, gAzB = 0.f, gAnB = 0.f;
    float gBrA = 0.f, gBzA = 0.f, gBnA = 0.f, gBrB = 0.f, gBzB = 0.f, gBnB = 0.f;
    if (act) {
        gArA = gxpA[0]; gAzA = gxpA[256]; gAnA = gxpA[512];
        gArB = gxpA[1]; gAzB = gxpA[257]; gAnB = gxpA[513];
        gBrA = gxpB[0]; gBzA = gxpB[256]; gBnA = gxpB[512];
        gBrB = gxpB[1]; gBzB = gxpB[257]; gBnB = gxpB[513];
    }

#pragma unroll 1
    for (int u = 0; u < tc; ++u) {
        const int tg   = gbase + u;
        const int par  = tg & 1;
        const int par1 = (tg + 1) & 1;
        const unsigned long long ver =
            (unsigned long long)(unsigned)(tg + 1) << 32;

        // ---- out-store step u-1, all 4 batches (hst stable since bar3) ----
        if (u > 0 && t < 64) {
            float4 o;
            o.x = hst[n_o][4 * f_o];     o.y = hst[n_o][4 * f_o + 1];
            o.z = hst[n_o][4 * f_o + 2]; o.w = hst[n_o][4 * f_o + 3];
            *(float4*)(out + ((size_t)(4 * g + n_o) * T_SZ + (tg - 1)) * H_SZ + u0 + 4 * f_o) = o;
        }

        // ---- poll A h(tg) (published ~1.5 phases ago -> first probe hits) ----
        {
            unsigned long long* sb = xch + xsl(g, par, n_loc, un);
            const unsigned want = (unsigned)tg;
            unsigned long long v = __hip_atomic_load(sb, __ATOMIC_RELAXED, __HIP_MEMORY_SCOPE_AGENT);
            int sp = 0;
            while ((unsigned)(v >> 32) != want && ++sp < SPIN_MAX) {
                __builtin_amdgcn_s_sleep(1);
                v = __hip_atomic_load(sb, __ATOMIC_RELAXED, __HIP_MEMORY_SCOPE_AGENT);
            }
            hlA[n_loc][wofs] = __uint_as_float((unsigned)v);
        }
        __syncthreads();                                   // bar1: hlA visible

        // ---- prefetch gxA(u+1) ----
        float pArA = 0.f, pAzA = 0.f, pAnA = 0.f, pArB = 0.f, pAzB = 0.f, pAnB = 0.f;
        if (act && u + 1 < tc) {
            size_t go = (size_t)(u + 1) * G3;
            pArA = gxpA[go];     pAzA = gxpA[go + 256]; pAnA = gxpA[go + 512];
            pArB = gxpA[go + 1]; pAzB = gxpA[go + 257]; pAnB = gxpA[go + 513];
        }

        // ---- phase A: matvec + reduce + gates + publish ----
        {
            float s[12][2];
#pragma unroll
            for (int i = 0; i < 2; ++i) {
                const float* hr = hrA[i];
                float4 hv0 = *(const float4*)(hr);
                float4 hv1 = *(const float4*)(hr + 4);
                f32x2 h0 = (f32x2){hv0.x, hv0.y};
                f32x2 h1 = (f32x2){hv0.z, hv0.w};
                f32x2 h2 = (f32x2){hv1.x, hv1.y};
                f32x2 h3 = (f32x2){hv1.z, hv1.w};
                f32x2 z  = (f32x2){0.f, 0.f};
#pragma unroll
                for (int f = 0; f < 12; ++f) {
                    f32x2 a = pkfma(h0, wf[f][0],
                              pkfma(h1, wf[f][1],
                              pkfma(h2, wf[f][2],
                              pkfma(h3, wf[f][3], z))));
                    s[f][i] = a.x + a.y;
                }
            }
#pragma unroll
            for (int f = 0; f < 12; ++f) {
                s[f][0] += dppx<0xB1>(s[f][1]);    // xor1: batch-bit combine
                s[f][0] += dppx<0x4E>(s[f][0]);    // xor2
                s[f][0] += dppx<0x124>(s[f][0]);   // ror4
                s[f][0] += dppx<0x128>(s[f][0]);   // ror8
                s[f][0] += swzx<0x401F>(s[f][0]);  // xor16
            }
            if (act) {
                float srA = hi ? s[2][0]  : s[0][0];
                float srB = hi ? s[3][0]  : s[1][0];
                float szA = hi ? s[6][0]  : s[4][0];
                float szB = hi ? s[7][0]  : s[5][0];
                float snA = hi ? s[10][0] : s[8][0];
                float snB = hi ? s[11][0] : s[9][0];
                float holdA = hlA[nb][pua];
                float holdB = hlA[nb][pua + 1];
                float arA = srA + gArA + bsr0;
                float azA = szA + gAzA + bsz0;
                float anA = snA + gAnA + bsn0;
                float arB = srB + gArB + bsr1;
                float azB = szB + gAzB + bsz1;
                float anB = snB + gAnB + bsn1;
                float rA = 1.f / (1.f + expf(-arA));
                float zA = 1.f / (1.f + expf(-azA));
                float nA = tanhf(rA * anA);
                float rB = 1.f / (1.f + expf(-arB));
                float zB = 1.f / (1.f + expf(-azB));
                float nB = tanhf(rB * anB);
                float hnA = (1.f - zA) * holdA + zA * nA;
                float hnB = (1.f - zB) * holdB + zB * nB;
                hst[nb][ueA - u0]     = hnA;
                hst[nb][ueA - u0 + 1] = hnB;
                __hip_atomic_store(xch + xsl(g, par1, nb, ueA),
                                   ver | (unsigned long long)__float_as_uint(hnA),
                                   __ATOMIC_RELAXED, __HIP_MEMORY_SCOPE_AGENT);
                __hip_atomic_store(xch + xsl(g, par1, nb, ueA + 1),
                                   ver | (unsigned long long)__float_as_uint(hnB),
                                   __ATOMIC_RELAXED, __HIP_MEMORY_SCOPE_AGENT);
            }
            gArA = pArA; gAzA = pAzA; gAnA = pAnA;
            gArB = pArB; gAzB = pAzB; gAnB = pAnB;
        }

        // ---- poll B h(tg) (published one iteration ago -> instant) ----
        {
            unsigned long long* sb = xch + xsl(g, par, 2 + n_loc, un);
            const unsigned want = (unsigned)tg;
            unsigned long long v = __hip_atomic_load(sb, __ATOMIC_RELAXED, __HIP_MEMORY_SCOPE_AGENT);
            int sp = 0;
            while ((unsigned)(v >> 32) != want && ++sp < SPIN_MAX) {
                __builtin_amdgcn_s_sleep(1);
                v = __hip_atomic_load(sb, __ATOMIC_RELAXED, __HIP_MEMORY_SCOPE_AGENT);
            }
            hlB[n_loc][wofs] = __uint_as_float((unsigned)v);
        }
        __syncthreads();                                   // bar2: hlB visible

        // ---- prefetch gxB(u+1) ----
        float pBrA = 0.f, pBzA = 0.f, pBnA = 0.f, pBrB = 0.f, pBzB = 0.f, pBnB = 0.f;
        if (act && u + 1 < tc) {
            size_t go = (size_t)(u + 1) * G3;
            pBrA = gxpB[go];     pBzA = gxpB[go + 256]; pBnA = gxpB[go + 512];
            pBrB = gxpB[go + 1]; pBzB = gxpB[go + 257]; pBnB = gxpB[go + 513];
        }

        // ---- phase B: matvec + reduce + gates + publish ----
        {
            float s[12][2];
#pragma unroll
            for (int i = 0; i < 2; ++i) {
                const float* hr = hrB[i];
                float4 hv0 = *(const float4*)(hr);
                float4 hv1 = *(const float4*)(hr + 4);
                f32x2 h0 = (f32x2){hv0.x, hv0.y};
                f32x2 h1 = (f32x2){hv0.z, hv0.w};
                f32x2 h2 = (f32x2){hv1.x, hv1.y};
                f32x2 h3 = (f32x2){hv1.z, hv1.w};
                f32x2 z  = (f32x2){0.f, 0.f};
#pragma unroll
                for (int f = 0; f < 12; ++f) {
                    f32x2 a = pkfma(h0, wf[f][0],
                              pkfma(h1, wf[f][1],
                              pkfma(h2, wf[f][2],
                              pkfma(h3, wf[f][3], z))));
                    s[f][i] = a.x + a.y;
                }
            }
#pragma unroll
            for (int f = 0; f < 12; ++f) {
                s[f][0] += dppx<0xB1>(s[f][1]);
                s[f][0] += dppx<0x4E>(s[f][0]);
                s[f][0] += dppx<0x124>(s[f][0]);
                s[f][0] += dppx<0x128>(s[f][0]);
                s[f][0] += swzx<0x401F>(s[f][0]);
            }
            if (act) {
                float srA = hi ? s[2][0]  : s[0][0];
                float srB = hi ? s[3][0]  : s[1][0];
                float szA = hi ? s[6][0]  : s[4][0];
                float szB = hi ? s[7][0]  : s[5][0];
                float snA = hi ? s[10][0] : s[8][0];
                float snB = hi ? s[11][0] : s[9][0];
                float holdA = hlB[nb][pua];
                float holdB = hlB[nb][pua + 1];
                float arA = srA + gBrA + bsr0;
                float azA = szA + gBzA + bsz0;
                float anA = snA + gBnA + bsn0;
                float arB = srB + gBrB + bsr1;
                float azB = szB + gBzB + bsz1;
                float anB = snB + gBnB + bsn1;
                float rA = 1.f / (1.f + expf(-arA));
                float zA = 1.f / (1.f + expf(-azA));
                float nA = tanhf(rA * anA);
                float rB = 1.f / (1.f + expf(-arB));
                float zB = 1.f / (1.f + expf(-azB));
                float nB = tanhf(rB * anB);
                float hnA = (1.f - zA) * holdA + zA * nA;
                float hnB = (1.f - zB) * holdB + zB * nB;
                hst[2 + nb][ueA - u0]     = hnA;
                hst[2 + nb][ueA - u0 + 1] = hnB;
                __hip_atomic_store(xch + xsl(g, par1, 2 + nb, ueA),
                                   ver | (unsigned long long)__float_as_uint(hnA),
                                   __ATOMIC_RELAXED, __HIP_MEMORY_SCOPE_AGENT);
                __hip_atomic_store(xch + xsl(g, par1, 2 + nb, ueA + 1),
                                   ver | (unsigned long long)__float_as_uint(hnB),
                                   __ATOMIC_RELAXED, __HIP_MEMORY_SCOPE_AGENT);
            }
            gBrA = pBrA; gBzA = pBzA; gBnA = pBnA;
            gBrB = pBrB; gBzB = pBzB; gBnB = pBnB;
        }
        __syncthreads();   // bar3: hlB reads done; hst visible; publishes drained
    }

    // ---- flush last step's out rows (+ h_last) ----
    if (t < 64) {
        float4 o;
        o.x = hst[n_o][4 * f_o];     o.y = hst[n_o][4 * f_o + 1];
        o.z = hst[n_o][4 * f_o + 2]; o.w = hst[n_o][4 * f_o + 3];
        *(float4*)(out + ((size_t)(4 * g + n_o) * T_SZ + (gbase + tc - 1)) * H_SZ + u0 + 4 * f_o) = o;
        if (isLast)
            *(float4*)(out + (size_t)B_SZ * T_SZ * H_SZ
                           + (size_t)(4 * g + n_o) * H_SZ + u0 + 4 * f_o) = o;
    }
}

// ---------------- host ----------------
extern "C" void kernel_launch(void* const* d_in, const int* in_sizes, int n_in,
                              void* d_out, int out_size, void* d_ws, size_t ws_size,
                              hipStream_t stream) {
    const float* x   = (const float*)d_in[0];
    const float* h0  = (const float*)d_in[1];
    const float* wih = (const float*)d_in[2];
    const float* whh = (const float*)d_in[3];
    const float* bih = (const float*)d_in[4];
    const float* bhh = (const float*)d_in[5];
    float* out = (float*)d_out;

    char* ws = (char*)d_ws;
    const size_t xchB = (size_t)NGRP * 2 * 4 * 256 * 8;   // 512 KiB
    unsigned long long* xch = (unsigned long long*)ws;
    float* gxb = (float*)(ws + xchB);

    int tcShift = 10;
    while (tcShift > 0 &&
           xchB + (786432ull << tcShift) > ws_size) --tcShift;
    const int TC  = 1 << tcShift;
    const int nCh = T_SZ / TC;

    prep_kernel<<<dim3(256), dim3(256), 0, stream>>>(h0, xch);
    for (int c = 0; c < nCh; ++c) {
        gemm_x_kernel<<<dim3(B_SZ * TC / 64, 6), dim3(256), 0, stream>>>(
            x, wih, gxb, c, tcShift);
        gru_kernel<<<dim3(B_SZ), dim3(512), 0, stream>>>(
            gxb, whh, bih, bhh, xch, out, c * TC, TC, (c == nCh - 1) ? 1 : 0);
    }
}